// Round 7
// baseline (202.366 us; speedup 1.0000x reference)
//
#include <hip/hip_runtime.h>

#define BB   8192   // batch (M)
#define DIN  4096   // K
#define DOUT 2048   // N

typedef unsigned short ushort_t;
typedef __attribute__((ext_vector_type(8))) short bf16x8;   // 8 bf16 (4 VGPRs)
typedef __attribute__((ext_vector_type(4))) float f32x4;    // 4 fp32 acc

// round-to-nearest-even fp32 -> bf16 bits (used by maskT)
__device__ inline ushort_t f2bf(float f) {
    union { float f; unsigned u; } v; v.f = f;
    unsigned u = v.u;
    return (ushort_t)((u + 0x7fffu + ((u >> 16) & 1u)) >> 16);
}

// async global->LDS, 16B per lane; LDS dest = wave-uniform base (+lane*16 implicit)
#define GLOAD16(g, s)                                                        \
    __builtin_amdgcn_global_load_lds(                                        \
        (const __attribute__((address_space(1))) void*)(g),                  \
        (__attribute__((address_space(3))) void*)(s), 16, 0, 0)

#define FENCE() asm volatile("" ::: "memory")
#define BAR()   do { FENCE(); __builtin_amdgcn_s_barrier(); FENCE(); } while (0)
#define VMCNT(n) asm volatile("s_waitcnt vmcnt(" #n ")" ::: "memory")
#define LGKM0()  asm volatile("s_waitcnt lgkmcnt(0)" ::: "memory")

// ---------------- pre-pass: WT[n][k] = bf16(kernel[k][n]*map[k][n]) ----------------
__global__ __launch_bounds__(256) void maskT(const float* __restrict__ Kn,
                                             const float* __restrict__ Mp,
                                             ushort_t* __restrict__ WT) {
    __shared__ ushort_t t[32][33];
    const int n0 = blockIdx.x * 32;
    const int k0 = blockIdx.y * 32;
    const int tx = threadIdx.x, ty = threadIdx.y;
    #pragma unroll
    for (int i = ty; i < 32; i += 8) {
        size_t idx = (size_t)(k0 + i) * DOUT + (n0 + tx);
        t[i][tx] = f2bf(Kn[idx] * Mp[idx]);
    }
    __syncthreads();
    #pragma unroll
    for (int i = ty; i < 32; i += 8) {
        WT[(size_t)(n0 + i) * DIN + (k0 + tx)] = t[tx][i];
    }
}

// ---------------- main GEMM: 256x256 tile, BK=64, 8 waves ----------------
// A fp32 reg-staged (global->reg->cvt->ds_write), B bf16 via gload_lds.
// Leash schedule (fix of the R6 regression): ALL of tile t+1's loads issue
// at q0 (8 A dwordx4 + 4 B gload_lds). q2 post-MFMA: VMCNT(4) retires the
// 8 A loads (2-phase leash; B stays in flight), write both A halves to LDS.
// q3 post-MFMA: VMCNT(0) retires B (3-phase leash, instant), LGKM0, swap.
// No 1-phase leash anywhere; queue never empty mid-tile except at swap.
// Swizzle both sides: byte_col ^= (row&7)<<4 within each 128B row.
// LDS: buf d: A half h at d*65536+h*16384 ([128][64] bf16); B at +32768.
__global__ __launch_bounds__(512) void gemm8(const float* __restrict__ A,      // [M][K] f32
                                             const ushort_t* __restrict__ BT,  // [N][K] bf16
                                             const float* __restrict__ bias,   // [N]
                                             float* __restrict__ C) {          // [M][N] f32
    constexpr int K = DIN, N = DOUT;
    constexpr int NT = K / 64;           // 64 K-tiles
    extern __shared__ char sb[];         // 128 KiB

    const int tid  = threadIdx.x;
    const int lane = tid & 63;
    const int w    = tid >> 6;           // wave 0..7
    const int wr   = w >> 2;             // 0..1  (M half)
    const int wcn  = w & 3;              // 0..3  (N quarter)
    const int l15  = lane & 15;

    // bijective XCD swizzle: 256 blocks, 256 % 8 == 0
    const int orig = blockIdx.y * 8 + blockIdx.x;
    const int swz  = (orig & 7) * 32 + (orig >> 3);
    const int n0   = (swz & 7) * 256;    // N tile
    const int m0   = (swz >> 3) * 256;   // M tile

    // ---- B staging: chunk (h,c) = rows c*8..c*8+7 of half h; lane l -> row c*8+(l>>3),
    // LDS slot (l&7); global col16 = (l&7)^(l>>3)  (inverse swizzle, row&7 = l>>3)
    const int srow = lane >> 3;
    const int scol = ((lane & 7) ^ srow) * 8;
    const ushort_t* Bb = BT + (size_t)(n0 + srow) * K + scol;
    auto stgB = [&](int buf, int kt, int h, int c) {
        GLOAD16(Bb + (size_t)(h * 128 + c * 8) * K + kt * 64,
                sb + buf * 65536 + 32768 + h * 16384 + c * 1024);
    };

    // ---- A reg staging: load (hf,j) -> row hf*128+j*32+(tid>>4), floats (tid&15)*4..+3.
    // Per instruction: 16-lane groups read 256B contiguous (coalesced).
    const float* Aft = A + (size_t)(m0 + (tid >> 4)) * K + (tid & 15) * 4;
    float4 apf[8];                        // [hf*4 + j]
    auto issueA = [&](int kt) {
        #pragma unroll
        for (int hf = 0; hf < 2; ++hf)
            #pragma unroll
            for (int j = 0; j < 4; ++j)
                apf[hf * 4 + j] =
                    *(const float4*)(Aft + (size_t)(hf * 128 + j * 32) * K + kt * 64);
    };
    // LDS write offset: row*128 + ((col8*8) ^ ((row&7)<<4)); row&7 = (tid>>4)&7
    const int awoff = (tid >> 4) * 128 + (((tid & 15) * 8) ^ (((tid >> 4) & 7) << 4));
    auto writeA = [&](int buf) {
        #pragma unroll
        for (int hf = 0; hf < 2; ++hf)
            #pragma unroll
            for (int j = 0; j < 4; ++j) {
                uint2 p;
                float4 v = apf[hf * 4 + j];
                asm("v_cvt_pk_bf16_f32 %0, %1, %2" : "=v"(p.x) : "v"(v.x), "v"(v.y));
                asm("v_cvt_pk_bf16_f32 %0, %1, %2" : "=v"(p.y) : "v"(v.z), "v"(v.w));
                *(uint2*)(sb + buf * 65536 + hf * 16384 + j * 4096 + awoff) = p;
            }
    };

    // ---- fragment ds_read: row = <mult of 16> + l15 -> row&7 = l15&7 ----
    const int fxor = (l15 & 7) << 4;
    const int kq   = (lane >> 4) * 16;   // 16B col within K=32 sub-tile

    f32x4 acc[8][4] = {};   // 8 m-frags x 4 n-frags
    bf16x8 bfk[4];          // B frags for current ks (persist 2 phases)

    // ---- prologue: tile 0 -> buf 0
    issueA(0);
    stgB(0, 0, 0, w); stgB(0, 0, 0, 8 + w);
    stgB(0, 0, 1, w); stgB(0, 0, 1, 8 + w);
    VMCNT(4);          // A regs landed
    writeA(0);
    VMCNT(0); LGKM0(); // B + A ds_writes visible
    BAR();

    for (int t = 0; t < NT; ++t) {
        const int  cur = t & 1;
        const int  nxt = cur ^ 1;
        const bool pf  = (t + 1 < NT);
        const char* Abase = sb + cur * 65536 + wr * 16384;
        const char* Bbase = sb + cur * 65536 + 32768 + wcn * 8192;

        #pragma unroll
        for (int q = 0; q < 4; ++q) {
            const int mh = q & 1;        // m-half of the wave's 8 m-frags
            const int ks = q >> 1;       // K=32 sub-tile within BK=64
            bf16x8 af[4];
            #pragma unroll
            for (int mm = 0; mm < 4; ++mm)
                af[mm] = *(const bf16x8*)(Abase + (mh * 4 + mm) * 2048 + l15 * 128 +
                                          ((ks * 64 + kq) ^ fxor));
            if (mh == 0) {
                #pragma unroll
                for (int n = 0; n < 4; ++n)
                    bfk[n] = *(const bf16x8*)(Bbase + n * 2048 + l15 * 128 +
                                              ((ks * 64 + kq) ^ fxor));
            }
            if (q == 0 && pf) {
                issueA(t + 1);                                 // 8 dwordx4 (oldest)
                stgB(nxt, t + 1, 0, w); stgB(nxt, t + 1, 0, 8 + w);
                stgB(nxt, t + 1, 1, w); stgB(nxt, t + 1, 1, 8 + w);
            }
            BAR();
            __builtin_amdgcn_s_setprio(1);
            #pragma unroll
            for (int mm = 0; mm < 4; ++mm)
                #pragma unroll
                for (int n = 0; n < 4; ++n)
                    acc[mh * 4 + mm][n] = __builtin_amdgcn_mfma_f32_16x16x32_bf16(
                        af[mm], bfk[n], acc[mh * 4 + mm][n], 0, 0, 0);
            __builtin_amdgcn_s_setprio(0);
            if (q == 2 && pf) {
                VMCNT(4);            // 8 A loads (oldest) landed; B's 4 still in flight
                writeA(nxt);         // 16 cvt + 8 ds_write, off the load path
            }
            if (q == 3 && pf) {
                VMCNT(0);            // B leash 3 phases -> retires ~instantly
                LGKM0();             // A ds_writes visible before buffer-swap barrier
            }
            BAR();
        }
    }

    // ---- epilogue: C/D layout col=lane&15, row=(lane>>4)*4+j; fused bias ----
    #pragma unroll
    for (int n = 0; n < 4; ++n) {
        const int col = n0 + wcn * 64 + n * 16 + l15;
        const float bv = bias[col];
        #pragma unroll
        for (int m = 0; m < 8; ++m) {
            const int r0 = m0 + wr * 128 + m * 16 + (lane >> 4) * 4;
            #pragma unroll
            for (int j = 0; j < 4; ++j)
                C[(size_t)(r0 + j) * N + col] = acc[m][n][j] + bv;
        }
    }
}

// ---------------- fallback (ws too small): fp32 LDS-tiled GEMM ----------------
__global__ __launch_bounds__(1024) void gemm_fb(const float* __restrict__ A,
                                                const float* __restrict__ Kn,
                                                const float* __restrict__ Mp,
                                                const float* __restrict__ bias,
                                                float* __restrict__ C) {
    __shared__ float As[32][33];
    __shared__ float Bs[32][33];
    const int tx = threadIdx.x, ty = threadIdx.y;
    const int row = blockIdx.y * 32 + ty;
    const int col = blockIdx.x * 32 + tx;
    float acc = 0.f;
    for (int kt = 0; kt < DIN; kt += 32) {
        As[ty][tx] = A[(size_t)row * DIN + kt + tx];
        size_t bidx = (size_t)(kt + ty) * DOUT + col;
        Bs[ty][tx] = Kn[bidx] * Mp[bidx];
        __syncthreads();
        #pragma unroll
        for (int kk = 0; kk < 32; ++kk)
            acc += As[ty][kk] * Bs[kk][tx];
        __syncthreads();
    }
    C[(size_t)row * DOUT + col] = acc + bias[col];
}

extern "C" void kernel_launch(void* const* d_in, const int* in_sizes, int n_in,
                              void* d_out, int out_size, void* d_ws, size_t ws_size,
                              hipStream_t stream) {
    const float* inputs = (const float*)d_in[0];   // [8192,4096]
    const float* kernel = (const float*)d_in[1];   // [4096,2048]
    const float* bias   = (const float*)d_in[2];   // [2048]
    const float* map    = (const float*)d_in[3];   // [4096,2048]
    float* out = (float*)d_out;                    // [8192,2048]

    const size_t wbytes = (size_t)DIN * DOUT * sizeof(ushort_t); // 16 MiB

    if (ws_size >= wbytes) {
        ushort_t* WT = (ushort_t*)d_ws;

        static bool attr_set = false;
        if (!attr_set) {
            hipFuncSetAttribute((const void*)gemm8,
                                hipFuncAttributeMaxDynamicSharedMemorySize, 131072);
            attr_set = true;
        }

        maskT<<<dim3(DOUT / 32, DIN / 32), dim3(32, 8), 0, stream>>>(kernel, map, WT);
        gemm8<<<dim3(DOUT / 256, BB / 256), 512, 131072, stream>>>(inputs, WT, bias, out);
    } else {
        gemm_fb<<<dim3(DOUT / 32, BB / 32), dim3(32, 32), 0, stream>>>(inputs, kernel, map,
                                                                       bias, out);
    }
}

// Round 8
// 177.373 us; speedup vs baseline: 1.1409x; 1.1409x over previous
//
#include <hip/hip_runtime.h>

#define BB   8192   // batch (M)
#define DIN  4096   // K
#define DOUT 2048   // N

typedef unsigned short ushort_t;
typedef __attribute__((ext_vector_type(8))) short bf16x8;   // 8 bf16 (4 VGPRs)
typedef __attribute__((ext_vector_type(4))) float f32x4;    // 4 fp32 acc

// round-to-nearest-even fp32 -> bf16 bits
__device__ inline ushort_t f2bf(float f) {
    union { float f; unsigned u; } v; v.f = f;
    unsigned u = v.u;
    return (ushort_t)((u + 0x7fffu + ((u >> 16) & 1u)) >> 16);
}

// async global->LDS, 16B per lane; LDS dest = wave-uniform base (+lane*16 implicit)
#define GLOAD16(g, s)                                                        \
    __builtin_amdgcn_global_load_lds(                                        \
        (const __attribute__((address_space(1))) void*)(g),                  \
        (__attribute__((address_space(3))) void*)(s), 16, 0, 0)

#define FENCE() asm volatile("" ::: "memory")
#define BAR()   do { FENCE(); __builtin_amdgcn_s_barrier(); FENCE(); } while (0)
#define VMCNT(n) asm volatile("s_waitcnt vmcnt(" #n ")" ::: "memory")

// ---------------- pre-pass 1: inputs fp32 -> bf16 ----------------
struct __align__(8) us4 { ushort_t x, y, z, w; };

__global__ __launch_bounds__(256) void convA(const float4* __restrict__ in,
                                             us4* __restrict__ out, int n4) {
    int i = blockIdx.x * blockDim.x + threadIdx.x;
    int stride = gridDim.x * blockDim.x;
    for (; i < n4; i += stride) {
        float4 v = in[i];
        us4 o;
        o.x = f2bf(v.x); o.y = f2bf(v.y); o.z = f2bf(v.z); o.w = f2bf(v.w);
        out[i] = o;
    }
}

// ---------------- pre-pass 2: WT[n][k] = bf16(kernel[k][n]*map[k][n]) ----------------
__global__ __launch_bounds__(256) void maskT(const float* __restrict__ Kn,
                                             const float* __restrict__ Mp,
                                             ushort_t* __restrict__ WT) {
    __shared__ ushort_t t[32][33];
    const int n0 = blockIdx.x * 32;
    const int k0 = blockIdx.y * 32;
    const int tx = threadIdx.x, ty = threadIdx.y;
    #pragma unroll
    for (int i = ty; i < 32; i += 8) {
        size_t idx = (size_t)(k0 + i) * DOUT + (n0 + tx);
        t[i][tx] = f2bf(Kn[idx] * Mp[idx]);
    }
    __syncthreads();
    #pragma unroll
    for (int i = ty; i < 32; i += 8) {
        WT[(size_t)(n0 + i) * DIN + (k0 + tx)] = t[tx][i];
    }
}

// ---------------- main GEMM: 256x256 tile, BK=64, 8 waves, 4 phases ----------------
// Proven R3 structure (125us, MfmaUtil 46%, 0 conflicts), ONE change: all 8
// global_load_lds for tile t+1 issue at q0 (R3 spread them q0-q3, leaving a
// 1-phase leash on A-low); single VMCNT(0) at q3-end -> every load has a
// 3-3.7-phase (~500-700cy) leash. All staging is DMA (no data returns to the
// wave) -- the R6/R7 reg-staging regression is removed.
// LDS (dynamic, 128 KiB): buf d: A half h at d*65536 + h*16384 ([128][64] bf16),
//                         B half h at d*65536 + 32768 + h*16384.
// Bank swizzle both sides: byte_col ^= (row&7)<<4 within each 128B row.
__global__ __launch_bounds__(512) void gemm8(const ushort_t* __restrict__ A,   // [M][K] bf16
                                             const ushort_t* __restrict__ BT,  // [N][K] bf16
                                             const float* __restrict__ bias,   // [N]
                                             float* __restrict__ C) {          // [M][N] f32
    constexpr int K = DIN, N = DOUT;
    constexpr int NT = K / 64;           // 64 K-tiles
    extern __shared__ char sb[];         // 128 KiB

    const int tid  = threadIdx.x;
    const int lane = tid & 63;
    const int w    = tid >> 6;           // wave 0..7
    const int wr   = w >> 2;             // 0..1  (M half)
    const int wcn  = w & 3;              // 0..3  (N quarter)
    const int l15  = lane & 15;

    // bijective XCD swizzle: 256 blocks, 256 % 8 == 0
    const int orig = blockIdx.y * 8 + blockIdx.x;
    const int swz  = (orig & 7) * 32 + (orig >> 3);
    const int n0   = (swz & 7) * 256;    // N tile
    const int m0   = (swz >> 3) * 256;   // M tile

    // ---- staging source: chunk (h,c) = rows c*8..c*8+7 of half h; lane l ->
    // row c*8+(l>>3), LDS 16B slot (l&7); global col16 = (l&7)^(l>>3)
    const int srow = lane >> 3;
    const int scol = ((lane & 7) ^ srow) * 8;
    const ushort_t* Ab = A  + (size_t)(m0 + srow) * K + scol;
    const ushort_t* Bb = BT + (size_t)(n0 + srow) * K + scol;

    auto stgA = [&](int buf, int kt, int h, int c) {
        GLOAD16(Ab + (size_t)(h * 128 + c * 8) * K + kt * 64,
                sb + buf * 65536 + h * 16384 + c * 1024);
    };
    auto stgB = [&](int buf, int kt, int h, int c) {
        GLOAD16(Bb + (size_t)(h * 128 + c * 8) * K + kt * 64,
                sb + buf * 65536 + 32768 + h * 16384 + c * 1024);
    };

    // ---- fragment ds_read: row = <mult of 16> + l15 -> row&7 = l15&7 ----
    const int fxor = (l15 & 7) << 4;     // swizzle XOR on byte column
    const int kq   = (lane >> 4) * 16;   // 16B col within K=32 sub-tile

    f32x4 acc[8][4] = {};   // 8 m-frags x 4 n-frags
    bf16x8 bf[4][2];        // B frags: n x ks, live across the 4 phases of a tile

    // ---- prologue: stage tile 0 into buf 0 (8 DMA loads), drain, go
    stgB(0, 0, 0, w); stgB(0, 0, 0, 8 + w);
    stgB(0, 0, 1, w); stgB(0, 0, 1, 8 + w);
    stgA(0, 0, 0, w); stgA(0, 0, 1, w);
    stgA(0, 0, 0, 8 + w); stgA(0, 0, 1, 8 + w);
    VMCNT(0);
    BAR();

    for (int t = 0; t < NT; ++t) {
        const int  cur = t & 1;
        const int  nxt = cur ^ 1;
        const bool pf  = (t + 1 < NT);
        const char* Abase = sb + cur * 65536 + wr * 16384;
        const char* Bbase = sb + cur * 65536 + 32768 + (wcn >> 1) * 16384 + (wcn & 1) * 8192;

        #pragma unroll
        for (int q = 0; q < 4; ++q) {
            // -- ds reads for this quadrant (A rows [32q,32q+32), + all B at q0)
            bf16x8 af[2][2];
            #pragma unroll
            for (int mm = 0; mm < 2; ++mm)
                #pragma unroll
                for (int ks = 0; ks < 2; ++ks)
                    af[mm][ks] = *(const bf16x8*)(Abase + (2 * q + mm) * 2048 + l15 * 128 +
                                                  ((ks * 64 + kq) ^ fxor));
            if (q == 0) {
                #pragma unroll
                for (int n = 0; n < 4; ++n)
                    #pragma unroll
                    for (int ks = 0; ks < 2; ++ks)
                        bf[n][ks] = *(const bf16x8*)(Bbase + n * 2048 + l15 * 128 +
                                                     ((ks * 64 + kq) ^ fxor));
                // -- issue ALL of tile t+1's staging here (3-3.7-phase leash)
                if (pf) {
                    stgB(nxt, t + 1, 0, w); stgB(nxt, t + 1, 0, 8 + w);
                    stgB(nxt, t + 1, 1, w); stgB(nxt, t + 1, 1, 8 + w);
                    stgA(nxt, t + 1, 0, w); stgA(nxt, t + 1, 1, w);
                    stgA(nxt, t + 1, 0, 8 + w); stgA(nxt, t + 1, 1, 8 + w);
                }
            }
            BAR();   // phase lock; frag data deps handled by compiler lgkm waits
            __builtin_amdgcn_s_setprio(1);
            #pragma unroll
            for (int ks = 0; ks < 2; ++ks)
                #pragma unroll
                for (int mm = 0; mm < 2; ++mm)
                    #pragma unroll
                    for (int n = 0; n < 4; ++n)
                        acc[2 * q + mm][n] = __builtin_amdgcn_mfma_f32_16x16x32_bf16(
                            af[mm][ks], bf[n][ks], acc[2 * q + mm][n], 0, 0, 0);
            __builtin_amdgcn_s_setprio(0);
            if (q == 3) { VMCNT(0); }  // t+1's 8 DMAs (issued q0) landed; no-op at t=NT-1
            BAR();
        }
    }

    // ---- epilogue: C/D layout col=lane&15, row=(lane>>4)*4+j; fused bias ----
    #pragma unroll
    for (int n = 0; n < 4; ++n) {
        const int col = n0 + wcn * 64 + n * 16 + l15;
        const float bv = bias[col];
        #pragma unroll
        for (int m = 0; m < 8; ++m) {
            const int r0 = m0 + wr * 128 + m * 16 + (lane >> 4) * 4;
            #pragma unroll
            for (int j = 0; j < 4; ++j)
                C[(size_t)(r0 + j) * N + col] = acc[m][n][j] + bv;
        }
    }
}

// ---------------- fallback (ws too small): fp32 LDS-tiled GEMM ----------------
__global__ __launch_bounds__(1024) void gemm_fb(const float* __restrict__ A,
                                                const float* __restrict__ Kn,
                                                const float* __restrict__ Mp,
                                                const float* __restrict__ bias,
                                                float* __restrict__ C) {
    __shared__ float As[32][33];
    __shared__ float Bs[32][33];
    const int tx = threadIdx.x, ty = threadIdx.y;
    const int row = blockIdx.y * 32 + ty;
    const int col = blockIdx.x * 32 + tx;
    float acc = 0.f;
    for (int kt = 0; kt < DIN; kt += 32) {
        As[ty][tx] = A[(size_t)row * DIN + kt + tx];
        size_t bidx = (size_t)(kt + ty) * DOUT + col;
        Bs[ty][tx] = Kn[bidx] * Mp[bidx];
        __syncthreads();
        #pragma unroll
        for (int kk = 0; kk < 32; ++kk)
            acc += As[ty][kk] * Bs[kk][tx];
        __syncthreads();
    }
    C[(size_t)row * DOUT + col] = acc + bias[col];
}

extern "C" void kernel_launch(void* const* d_in, const int* in_sizes, int n_in,
                              void* d_out, int out_size, void* d_ws, size_t ws_size,
                              hipStream_t stream) {
    const float* inputs = (const float*)d_in[0];   // [8192,4096]
    const float* kernel = (const float*)d_in[1];   // [4096,2048]
    const float* bias   = (const float*)d_in[2];   // [2048]
    const float* map    = (const float*)d_in[3];   // [4096,2048]
    float* out = (float*)d_out;                    // [8192,2048]

    const size_t abytes = (size_t)BB * DIN * sizeof(ushort_t);   // 64 MiB
    const size_t wbytes = (size_t)DIN * DOUT * sizeof(ushort_t); // 16 MiB

    if (ws_size >= abytes + wbytes) {
        ushort_t* Abf = (ushort_t*)d_ws;
        ushort_t* WT  = (ushort_t*)((char*)d_ws + abytes);

        static bool attr_set = false;
        if (!attr_set) {
            hipFuncSetAttribute((const void*)gemm8,
                                hipFuncAttributeMaxDynamicSharedMemorySize, 131072);
            attr_set = true;
        }

        convA<<<2048, 256, 0, stream>>>((const float4*)inputs, (us4*)Abf,
                                        (int)((size_t)BB * DIN / 4));
        maskT<<<dim3(DOUT / 32, DIN / 32), dim3(32, 8), 0, stream>>>(kernel, map, WT);
        gemm8<<<dim3(DOUT / 256, BB / 256), 512, 131072, stream>>>(Abf, WT, bias, out);
    } else {
        gemm_fb<<<dim3(DOUT / 32, BB / 32), dim3(32, 32), 0, stream>>>(inputs, kernel, map,
                                                                       bias, out);
    }
}

// Round 9
// 174.564 us; speedup vs baseline: 1.1593x; 1.0161x over previous
//
#include <hip/hip_runtime.h>

#define BB   8192   // batch (M)
#define DIN  4096   // K
#define DOUT 2048   // N

typedef unsigned short ushort_t;
typedef __attribute__((ext_vector_type(8))) short bf16x8;   // 8 bf16 (4 VGPRs)
typedef __attribute__((ext_vector_type(4))) float f32x4;    // 4 fp32 acc

// round-to-nearest-even fp32 -> bf16 bits
__device__ inline ushort_t f2bf(float f) {
    union { float f; unsigned u; } v; v.f = f;
    unsigned u = v.u;
    return (ushort_t)((u + 0x7fffu + ((u >> 16) & 1u)) >> 16);
}

// async global->LDS, 16B per lane; LDS dest = wave-uniform base (+lane*16 implicit)
#define GLOAD16(g, s)                                                        \
    __builtin_amdgcn_global_load_lds(                                        \
        (const __attribute__((address_space(1))) void*)(g),                  \
        (__attribute__((address_space(3))) void*)(s), 16, 0, 0)

#define FENCE() asm volatile("" ::: "memory")
#define BAR()   do { FENCE(); __builtin_amdgcn_s_barrier(); FENCE(); } while (0)
#define VMCNT(n) asm volatile("s_waitcnt vmcnt(" #n ")" ::: "memory")

// ---------------- pre-pass 1: inputs fp32 -> bf16 ----------------
struct __align__(8) us4 { ushort_t x, y, z, w; };

__global__ __launch_bounds__(256) void convA(const float4* __restrict__ in,
                                             us4* __restrict__ out, int n4) {
    int i = blockIdx.x * blockDim.x + threadIdx.x;
    int stride = gridDim.x * blockDim.x;
    for (; i < n4; i += stride) {
        float4 v = in[i];
        us4 o;
        o.x = f2bf(v.x); o.y = f2bf(v.y); o.z = f2bf(v.z); o.w = f2bf(v.w);
        out[i] = o;
    }
}

// ---------------- pre-pass 2: WT[n][k] = bf16(kernel[k][n]*map[k][n]) ----------------
__global__ __launch_bounds__(256) void maskT(const float* __restrict__ Kn,
                                             const float* __restrict__ Mp,
                                             ushort_t* __restrict__ WT) {
    __shared__ ushort_t t[32][33];
    const int n0 = blockIdx.x * 32;
    const int k0 = blockIdx.y * 32;
    const int tx = threadIdx.x, ty = threadIdx.y;
    #pragma unroll
    for (int i = ty; i < 32; i += 8) {
        size_t idx = (size_t)(k0 + i) * DOUT + (n0 + tx);
        t[i][tx] = f2bf(Kn[idx] * Mp[idx]);
    }
    __syncthreads();
    #pragma unroll
    for (int i = ty; i < 32; i += 8) {
        WT[(size_t)(n0 + i) * DIN + (k0 + tx)] = t[tx][i];
    }
}

// ---------------- main GEMM: 256x256 tile, BK=32, 8 waves, 4-deep pipeline ----------
// T4 never-drain schedule: 4 LDS buffers (32KB each); tile t+3 staged during
// tile t (A at p0, B at p1, 2 gload_lds each); ONLY wait = VMCNT(8) at tile
// end, retiring exactly tile t+1's 4 loads (leash 4-5 phases ~2500cy >> 900cy
// HBM). Queue never drops below 8 in steady state.
// Packing (keeps 128B LDS rows at BK=32): pair p in [0,128) holds
// [row p | row p+128] x 32 K-cols. Slot swizzle: stored = logical ^ (p&7),
// logical slot = hf*4 + col16. Inverse applied to global source (DMA dest
// linear, rule 21); frag reads XOR (l15&7) -> 2-way max bank aliasing (free).
// Buffer b: A at b*32768 (16KB), B at +16384. 4 bufs = 128KB.
__global__ __launch_bounds__(512) void gemm8(const ushort_t* __restrict__ A,   // [M][K] bf16
                                             const ushort_t* __restrict__ BT,  // [N][K] bf16
                                             const float* __restrict__ bias,   // [N]
                                             float* __restrict__ C) {          // [M][N] f32
    constexpr int K = DIN, N = DOUT;
    constexpr int NT = K / 32;           // 128 K-tiles of BK=32
    extern __shared__ char sb[];         // 128 KiB

    const int tid  = threadIdx.x;
    const int lane = tid & 63;
    const int w    = tid >> 6;           // wave 0..7
    const int wr   = w >> 2;             // 0..1  (M half: rows wr*128..+127)
    const int wcn  = w & 3;              // 0..3  (N quarter: cols wcn*64..+63)
    const int l15  = lane & 15;

    // bijective XCD swizzle: 256 blocks, 256 % 8 == 0
    const int orig = blockIdx.y * 8 + blockIdx.x;
    const int swz  = (orig & 7) * 32 + (orig >> 3);
    const int n0   = (swz & 7) * 256;    // N tile
    const int m0   = (swz >> 3) * 256;   // M tile

    // ---- staging source geometry (same form for A and B) ----
    // chunk c (0..15) = pairs c*8..c*8+7. Lane l -> pair c*8+(l>>3), stored
    // slot (l&7); logical slot sl = (l&7)^(l>>3) -> global row += (sl>>2)*128,
    // K col16 = sl&3.
    const int sl  = (lane & 7) ^ (lane >> 3);
    const int sro = (sl >> 2) * 128 + (lane >> 3);   // + c*8 at call site
    const int sco = (sl & 3) * 8;                    // bf16 elements
    const ushort_t* Ab = A  + (size_t)(m0 + sro) * K + sco;
    const ushort_t* Bb = BT + (size_t)(n0 + sro) * K + sco;

    auto stgA = [&](int buf, int kt, int c) {
        GLOAD16(Ab + (size_t)(c * 8) * K + kt * 32, sb + buf * 32768 + c * 1024);
    };
    auto stgB = [&](int buf, int kt, int c) {
        GLOAD16(Bb + (size_t)(c * 8) * K + kt * 32, sb + buf * 32768 + 16384 + c * 1024);
    };

    // ---- fragment ds_read offsets ----
    // A frag fm (0..7): rows wr*128 + fm*16 + l15 -> pair fm*16+l15, hf=wr.
    const int aslot = ((wr << 2) | (lane >> 4)) ^ (l15 & 7);
    const int aoff  = l15 * 128 + aslot * 16;                    // + fm*2048
    // B frag fn (0..3): rows wcn*64 + fn*16 + l15 -> pair (wcn&1)*64+fn*16+l15,
    // hf = wcn>>1.
    const int bslot = (((wcn >> 1) << 2) | (lane >> 4)) ^ (l15 & 7);
    const int boff  = 16384 + ((wcn & 1) * 64 + l15) * 128 + bslot * 16;  // + fn*2048

    f32x4 acc[8][4] = {};   // 8 m-frags x 4 n-frags
    bf16x8 bfk[4];          // B frags (persist across the tile's 2 phases)

    // ---- prologue: stage tiles 0,1,2 into bufs 0,1,2 (12 loads/thread) ----
    #pragma unroll
    for (int tt = 0; tt < 3; ++tt) {
        stgA(tt, tt, w); stgA(tt, tt, 8 + w);
        stgB(tt, tt, w); stgB(tt, tt, 8 + w);
    }
    VMCNT(8);   // tile 0's 4 loads retired; 8 remain in flight
    BAR();

    for (int t = 0; t < NT; ++t) {
        const char* base = sb + (t & 3) * 32768;
        const int   nb   = (t + 3) & 3;
        const bool  pf   = (t < NT - 3);

        // ======== phase 0: m-frags 0-3 x all B ========
        bf16x8 af[4];
        #pragma unroll
        for (int mm = 0; mm < 4; ++mm)
            af[mm] = *(const bf16x8*)(base + mm * 2048 + aoff);
        #pragma unroll
        for (int fn = 0; fn < 4; ++fn)
            bfk[fn] = *(const bf16x8*)(base + fn * 2048 + boff);
        if (pf) { stgA(nb, t + 3, w); stgA(nb, t + 3, 8 + w); }
        BAR();
        __builtin_amdgcn_s_setprio(1);
        #pragma unroll
        for (int mm = 0; mm < 4; ++mm)
            #pragma unroll
            for (int fn = 0; fn < 4; ++fn)
                acc[mm][fn] = __builtin_amdgcn_mfma_f32_16x16x32_bf16(
                    af[mm], bfk[fn], acc[mm][fn], 0, 0, 0);
        __builtin_amdgcn_s_setprio(0);
        BAR();

        // ======== phase 1: m-frags 4-7 ========
        #pragma unroll
        for (int mm = 0; mm < 4; ++mm)
            af[mm] = *(const bf16x8*)(base + (4 + mm) * 2048 + aoff);
        if (pf) { stgB(nb, t + 3, w); stgB(nb, t + 3, 8 + w); }
        BAR();
        __builtin_amdgcn_s_setprio(1);
        #pragma unroll
        for (int mm = 0; mm < 4; ++mm)
            #pragma unroll
            for (int fn = 0; fn < 4; ++fn)
                acc[4 + mm][fn] = __builtin_amdgcn_mfma_f32_16x16x32_bf16(
                    af[mm], bfk[fn], acc[4 + mm][fn], 0, 0, 0);
        __builtin_amdgcn_s_setprio(0);
        // ---- counted never-drain wait: retire exactly tile t+1's 4 loads ----
        if (t < NT - 3)       { VMCNT(8); }
        else if (t == NT - 3) { VMCNT(4); }
        else if (t == NT - 2) { VMCNT(0); }
        BAR();
    }

    // ---- epilogue: C/D layout col=lane&15, row=(lane>>4)*4+j; fused bias ----
    #pragma unroll
    for (int n = 0; n < 4; ++n) {
        const int col = n0 + wcn * 64 + n * 16 + l15;
        const float bv = bias[col];
        #pragma unroll
        for (int m = 0; m < 8; ++m) {
            const int r0 = m0 + wr * 128 + m * 16 + (lane >> 4) * 4;
            #pragma unroll
            for (int j = 0; j < 4; ++j)
                C[(size_t)(r0 + j) * N + col] = acc[m][n][j] + bv;
        }
    }
}

// ---------------- fallback (ws too small): fp32 LDS-tiled GEMM ----------------
__global__ __launch_bounds__(1024) void gemm_fb(const float* __restrict__ A,
                                                const float* __restrict__ Kn,
                                                const float* __restrict__ Mp,
                                                const float* __restrict__ bias,
                                                float* __restrict__ C) {
    __shared__ float As[32][33];
    __shared__ float Bs[32][33];
    const int tx = threadIdx.x, ty = threadIdx.y;
    const int row = blockIdx.y * 32 + ty;
    const int col = blockIdx.x * 32 + tx;
    float acc = 0.f;
    for (int kt = 0; kt < DIN; kt += 32) {
        As[ty][tx] = A[(size_t)row * DIN + kt + tx];
        size_t bidx = (size_t)(kt + ty) * DOUT + col;
        Bs[ty][tx] = Kn[bidx] * Mp[bidx];
        __syncthreads();
        #pragma unroll
        for (int kk = 0; kk < 32; ++kk)
            acc += As[ty][kk] * Bs[kk][tx];
        __syncthreads();
    }
    C[(size_t)row * DOUT + col] = acc + bias[col];
}

extern "C" void kernel_launch(void* const* d_in, const int* in_sizes, int n_in,
                              void* d_out, int out_size, void* d_ws, size_t ws_size,
                              hipStream_t stream) {
    const float* inputs = (const float*)d_in[0];   // [8192,4096]
    const float* kernel = (const float*)d_in[1];   // [4096,2048]
    const float* bias   = (const float*)d_in[2];   // [2048]
    const float* map    = (const float*)d_in[3];   // [4096,2048]
    float* out = (float*)d_out;                    // [8192,2048]

    const size_t abytes = (size_t)BB * DIN * sizeof(ushort_t);   // 64 MiB
    const size_t wbytes = (size_t)DIN * DOUT * sizeof(ushort_t); // 16 MiB

    if (ws_size >= abytes + wbytes) {
        ushort_t* Abf = (ushort_t*)d_ws;
        ushort_t* WT  = (ushort_t*)((char*)d_ws + abytes);

        static bool attr_set = false;
        if (!attr_set) {
            hipFuncSetAttribute((const void*)gemm8,
                                hipFuncAttributeMaxDynamicSharedMemorySize, 131072);
            attr_set = true;
        }

        convA<<<2048, 256, 0, stream>>>((const float4*)inputs, (us4*)Abf,
                                        (int)((size_t)BB * DIN / 4));
        maskT<<<dim3(DOUT / 32, DIN / 32), dim3(32, 8), 0, stream>>>(kernel, map, WT);
        gemm8<<<dim3(DOUT / 256, BB / 256), 512, 131072, stream>>>(Abf, WT, bias, out);
    } else {
        gemm_fb<<<dim3(DOUT / 32, BB / 32), dim3(32, 32), 0, stream>>>(inputs, kernel, map,
                                                                       bias, out);
    }
}